// Round 4
// baseline (359.794 us; speedup 1.0000x reference)
//
#include <hip/hip_runtime.h>
#include <math.h>

#define NB 256          // batch
#define XW 5048         // input row width
#define GENE 3000
#define DRUGW 2048
#define EPSF 1e-5f
#define NBLK 256        // persistent grid: 1 block/CU worst case, always co-resident

struct Params {
    const float* x;
    const int* cols0; const float* w0; const float* b0;
    const int* cols1; const float* w1; const float* b1;
    const float* w2;  const float* b2;
    const float* gg;  const float* eg;
    const float* g1;  const float* e1;
    const float* g2;  const float* e2;
    const float* Wd1; const float* bd1;
    const float* gd1; const float* ed1;
    const float* Wd2; const float* bd2;
    const float* gd2; const float* ed2;
    const float* Wd3; const float* bd3;
    const float* gd3; const float* ed3;
    const float* gf;  const float* ef;
    const float* Wf;  const float* bf;
    const float* ga;  const float* ea;
    const float* Wa;  const float* ba;
    const float* Wo;  const float* bo;
    float* out;
    float* gene_n; float* drug_n; float* h1i; float* h2i;
    float* fbn; float* d1n; float* d2n; float* o1n; float* part2; float* part1;
    unsigned int* bar;   // global barrier counter (memset to 0 each call)
};

// ---------------------------------------------------------------------------
// Device-scope global barrier (monotone counter; target = phase*NBLK).
// Release fence + agent-scope add; thread 0 spins on agent-scope load.
// All 256 blocks are guaranteed co-resident (1 block/CU capacity).
// ---------------------------------------------------------------------------
__device__ __forceinline__ void gbar(unsigned int* bar, unsigned int target) {
    __syncthreads();
    if (threadIdx.x == 0) {
        __threadfence();   // release: make this block's writes device-visible
        __hip_atomic_fetch_add(bar, 1u, __ATOMIC_RELEASE, __HIP_MEMORY_SCOPE_AGENT);
        while (__hip_atomic_load(bar, __ATOMIC_ACQUIRE, __HIP_MEMORY_SCOPE_AGENT) < target)
            __builtin_amdgcn_s_sleep(2);
        __threadfence();   // acquire: invalidate stale cached lines before reads
    }
    __syncthreads();
}

// ---------------------------------------------------------------------------
// BN epilogue: thread b = batch index owns values v[NR] of rows r0..r0+NR-1.
// ---------------------------------------------------------------------------
template<int NR, bool ILEAVE>
__device__ __forceinline__ void bn_fold(float (&v)[NR], int b,
        const float* __restrict__ g, const float* __restrict__ e,
        float* __restrict__ out) {
    __shared__ float sred[NR][4][2];
    __shared__ float s_ac[2][NR];
    int lane = b & 63, wv = b >> 6;
    float s1[NR], s2[NR];
    #pragma unroll
    for (int k = 0; k < NR; k++) { s1[k] = v[k]; s2[k] = v[k] * v[k]; }
    #pragma unroll
    for (int off = 32; off >= 1; off >>= 1) {
        #pragma unroll
        for (int k = 0; k < NR; k++) {
            s1[k] += __shfl_xor(s1[k], off);
            s2[k] += __shfl_xor(s2[k], off);
        }
    }
    if (lane == 0) {
        #pragma unroll
        for (int k = 0; k < NR; k++) { sred[k][wv][0] = s1[k]; sred[k][wv][1] = s2[k]; }
    }
    __syncthreads();
    if (b < NR) {
        float t1 = sred[b][0][0] + sred[b][1][0] + sred[b][2][0] + sred[b][3][0];
        float t2 = sred[b][0][1] + sred[b][1][1] + sred[b][2][1] + sred[b][3][1];
        float mu  = t1 * (1.0f / 256.0f);
        float var = t2 * (1.0f / 256.0f) - mu * mu;
        float rs  = rsqrtf(var + EPSF);
        float aa  = g[b] * rs;
        s_ac[0][b] = aa;
        s_ac[1][b] = e[b] - aa * mu;
    }
    __syncthreads();
    #pragma unroll
    for (int k = 0; k < NR; k++) {
        float w = s_ac[0][k] * v[k] + s_ac[1][k];
        if (ILEAVE) out[b * NR + k] = w;
        else        out[k * NB + b] = w;
    }
}

// ---------------------------------------------------------------------------
// Stage bodies (one "task" == one workgroup's worth of work)
// ---------------------------------------------------------------------------
__device__ __forceinline__ void inbn_task(const Params& p, int task, int t,
        float* tile, float* red1, float* red2, float* s_a, float* s_c) {
    int tx = t & 31, ty = t >> 5;
    int c0 = task * 32;
    int c = c0 + tx;
    bool valid = c < XW;
    float s1 = 0.f, s2 = 0.f;
    #pragma unroll 4
    for (int i = 0; i < 32; i++) {
        int r = ty * 32 + i;
        float v = valid ? p.x[(size_t)r * XW + c] : 0.f;
        tile[tx * 257 + r] = v;
        s1 += v; s2 += v * v;
    }
    red1[ty * 33 + tx] = s1; red2[ty * 33 + tx] = s2;
    __syncthreads();
    if (t < 32) {
        float t1 = 0.f, t2 = 0.f;
        #pragma unroll
        for (int k = 0; k < 8; k++) { t1 += red1[k * 33 + t]; t2 += red2[k * 33 + t]; }
        float mu  = t1 * (1.0f / 256.0f);
        float var = t2 * (1.0f / 256.0f) - mu * mu;
        float rs  = rsqrtf(var + EPSF);
        int col = c0 + t;
        float gv = 0.f, ev = 0.f;
        if (col < GENE)      { gv = p.gg[col];         ev = p.eg[col]; }
        else if (col < XW)   { gv = p.gd1[col - GENE]; ev = p.ed1[col - GENE]; }
        float aa = gv * rs;
        s_a[t] = aa; s_c[t] = ev - aa * mu;
    }
    __syncthreads();
    for (int cc = 0; cc < 32; cc++) {
        int col = c0 + cc;
        if (col >= XW) break;
        float w = s_a[cc] * tile[cc * 257 + t] + s_c[cc];
        if (col < GENE) p.gene_n[(size_t)col * NB + t] = w;
        else            p.drug_n[(size_t)(col - GENE) * NB + t] = w;
    }
    __syncthreads();   // tile reused by next task
}

__device__ __forceinline__ void splin0_task(const Params& p, int t, int b) {
    float acc[6] = {0.f, 0.f, 0.f, 0.f, 0.f, 0.f};
    int base = t * 180;
    for (int i = 0; i < 30; i++) {
        int ei = base + i * 6;
        int cc = p.cols0[ei];
        float v = p.gene_n[(size_t)cc * NB + b];
        #pragma unroll
        for (int k = 0; k < 6; k++) acc[k] += v * p.w0[ei + k];
    }
    float v6[6];
    #pragma unroll
    for (int k = 0; k < 6; k++) v6[k] = tanhf(acc[k] + p.b0[t * 6 + k]);
    // h1i interleaved: (t*256+b)*6+k
    bn_fold<6, true>(v6, b, p.g1 + t * 6, p.e1 + t * 6, p.h1i + (size_t)t * 6 * NB);
}

__device__ __forceinline__ void splin1_task(const Params& p, int o, int b) {
    float acc[6] = {0.f, 0.f, 0.f, 0.f, 0.f, 0.f};
    for (int pi = 0; pi < 5; pi++) {
        int qb = (o * 5 + pi) * 36;
        int cbase = p.cols1[qb];                 // = child*6
        const float* hv = p.h1i + (size_t)cbase * NB + b * 6;
        const float2* hv2 = (const float2*)hv;   // 8B aligned
        float2 a0 = hv2[0], a1 = hv2[1], a2 = hv2[2];
        float v[6] = {a0.x, a0.y, a1.x, a1.y, a2.x, a2.y};
        #pragma unroll
        for (int j = 0; j < 6; j++)
            #pragma unroll
            for (int i = 0; i < 6; i++) acc[i] += v[j] * p.w1[qb + i * 6 + j];
    }
    float v6[6];
    #pragma unroll
    for (int i = 0; i < 6; i++) v6[i] = tanhf(acc[i] + p.b1[o * 6 + i]);
    bn_fold<6, true>(v6, b, p.g2 + o * 6, p.e2 + o * 6, p.h2i + (size_t)o * 6 * NB);
}

// splin2: dense 24x2400; 16 tasks, each computes ALL 24 kf over 25 terms
__device__ __forceinline__ void splin2_part_task(const Params& p, int ch, int b) {
    float acc[24];
    #pragma unroll
    for (int kf = 0; kf < 24; kf++) acc[kf] = 0.f;
    int t0 = ch * 25;
    for (int t = t0; t < t0 + 25; t++) {
        const float* hv = p.h2i + (size_t)t * 6 * NB + b * 6;
        const float2* hv2 = (const float2*)hv;
        float2 a0 = hv2[0], a1 = hv2[1], a2 = hv2[2];
        float v[6] = {a0.x, a0.y, a1.x, a1.y, a2.x, a2.y};
        const float* wr = p.w2 + t * 144;
        #pragma unroll
        for (int kf = 0; kf < 24; kf++)
            #pragma unroll
            for (int j = 0; j < 6; j++) acc[kf] += v[j] * wr[kf * 6 + j];
    }
    #pragma unroll
    for (int kf = 0; kf < 24; kf++)
        p.part2[(size_t)(ch * 24 + kf) * NB + b] = acc[kf];
}

__device__ __forceinline__ void splin2_fin_task(const Params& p, int kf, int b) {
    float acc = p.b2[kf];
    #pragma unroll
    for (int ch = 0; ch < 16; ch++) acc += p.part2[(size_t)(ch * 24 + kf) * NB + b];
    float v[1] = { tanhf(acc) };
    bn_fold<1, false>(v, b, p.gf + kf, p.ef + kf, p.fbn + (size_t)kf * NB);
}

__device__ __forceinline__ void dense1_part_task(const Params& p, int sub, int b) {
    int jg = sub >> 3, ch = sub & 7;
    int j0 = jg * 4, c0 = ch * 256;
    float acc[4] = {0.f, 0.f, 0.f, 0.f};
    for (int c = c0; c < c0 + 256; c++) {
        float v = p.drug_n[(size_t)c * NB + b];
        #pragma unroll
        for (int jj = 0; jj < 4; jj++) acc[jj] += v * p.Wd1[(size_t)(j0 + jj) * DRUGW + c];
    }
    #pragma unroll
    for (int jj = 0; jj < 4; jj++)
        p.part1[(size_t)((j0 + jj) * 8 + ch) * NB + b] = acc[jj];
}

__device__ __forceinline__ void dense1_fin_task(const Params& p, int j, int b) {
    float acc = p.bd1[j];
    #pragma unroll
    for (int ch = 0; ch < 8; ch++) acc += p.part1[(size_t)(j * 8 + ch) * NB + b];
    float v[1] = { tanhf(acc) };
    bn_fold<1, false>(v, b, p.gd2 + j, p.ed2 + j, p.d1n + (size_t)j * NB);
}

__device__ __forceinline__ void dense8_task(const float* __restrict__ in_n,
        const float* __restrict__ W, const float* __restrict__ bias, int ncols,
        const float* __restrict__ g, const float* __restrict__ e,
        float* __restrict__ out_n, int j0, int b) {
    float acc[8] = {0.f,0.f,0.f,0.f,0.f,0.f,0.f,0.f};
    for (int c = 0; c < ncols; c++) {
        float v = in_n[(size_t)c * NB + b];
        #pragma unroll
        for (int jj = 0; jj < 8; jj++) acc[jj] += v * W[(size_t)(j0 + jj) * ncols + c];
    }
    float v[8];
    #pragma unroll
    for (int jj = 0; jj < 8; jj++) v[jj] = tanhf(acc[jj] + bias[j0 + jj]);
    bn_fold<8, false>(v, b, g + j0, e + j0, out_n + (size_t)j0 * NB);
}

__device__ __forceinline__ void final_task(const Params& p, int b) {
    float acc = p.ba[0];
    #pragma unroll
    for (int j = 0; j < 64; j++) acc += p.o1n[(size_t)j * NB + b] * p.Wa[j];
    p.out[b] = tanhf(acc) * p.Wo[0] + p.bo[0];
}

// ---------------------------------------------------------------------------
// Persistent mega kernel: 7 stages, 6 software grid barriers.
// ---------------------------------------------------------------------------
__global__ __launch_bounds__(256) void k_mega(Params p) {
    __shared__ float tile[32 * 257];
    __shared__ float red1[8 * 33];
    __shared__ float red2[8 * 33];
    __shared__ float s_a[32], s_c[32];
    const int b = threadIdx.x;

    // S0: input BN + transpose (158 tasks)
    for (int task = blockIdx.x; task < 158; task += gridDim.x)
        inbn_task(p, task, b, tile, red1, red2, s_a, s_c);
    gbar(p.bar, 1 * NBLK);

    // S1: splin0 (1500) || dense1_part (256)
    for (int task = blockIdx.x; task < 1756; task += gridDim.x) {
        if (task < 1500) splin0_task(p, task, b);
        else             dense1_part_task(p, task - 1500, b);
    }
    gbar(p.bar, 2 * NBLK);

    // S2: splin1 (400) || dense1_fin (128)
    for (int task = blockIdx.x; task < 528; task += gridDim.x) {
        if (task < 400) splin1_task(p, task, b);
        else            dense1_fin_task(p, task - 400, b);
    }
    gbar(p.bar, 3 * NBLK);

    // S3: splin2_part (16) || dense2 (8)
    for (int task = blockIdx.x; task < 24; task += gridDim.x) {
        if (task < 16) splin2_part_task(p, task, b);
        else dense8_task(p.d1n, p.Wd2, p.bd2, 128, p.gd3, p.ed3, p.d2n, (task - 16) * 8, b);
    }
    gbar(p.bar, 4 * NBLK);

    // S4: splin2_fin (24) || dense3 (4)
    for (int task = blockIdx.x; task < 28; task += gridDim.x) {
        if (task < 24) splin2_fin_task(p, task, b);
        else dense8_task(p.d2n, p.Wd3, p.bd3, 64, p.gf + 24, p.ef + 24,
                         p.fbn + 24 * NB, (task - 24) * 8, b);
    }
    gbar(p.bar, 5 * NBLK);

    // S5: densef (8)
    for (int task = blockIdx.x; task < 8; task += gridDim.x)
        dense8_task(p.fbn, p.Wf, p.bf, 56, p.ga, p.ea, p.o1n, task * 8, b);
    gbar(p.bar, 6 * NBLK);

    // S6: final head (1)
    if (blockIdx.x == 0)
        final_task(p, b);
}

extern "C" void kernel_launch(void* const* d_in, const int* in_sizes, int n_in,
                              void* d_out, int out_size, void* d_ws, size_t ws_size,
                              hipStream_t stream) {
    Params p;
    p.x    = (const float*)d_in[0];
    p.cols0 = (const int*)d_in[2];
    p.w0   = (const float*)d_in[3];
    p.b0   = (const float*)d_in[4];
    p.cols1 = (const int*)d_in[6];
    p.w1   = (const float*)d_in[7];
    p.b1   = (const float*)d_in[8];
    p.w2   = (const float*)d_in[11];
    p.b2   = (const float*)d_in[12];
    p.gg   = (const float*)d_in[13];
    p.eg   = (const float*)d_in[14];
    p.g1   = (const float*)d_in[15];
    p.e1   = (const float*)d_in[16];
    p.g2   = (const float*)d_in[17];
    p.e2   = (const float*)d_in[18];
    p.Wd1  = (const float*)d_in[19];
    p.bd1  = (const float*)d_in[20];
    p.gd1  = (const float*)d_in[21];
    p.ed1  = (const float*)d_in[22];
    p.Wd2  = (const float*)d_in[23];
    p.bd2  = (const float*)d_in[24];
    p.gd2  = (const float*)d_in[25];
    p.ed2  = (const float*)d_in[26];
    p.Wd3  = (const float*)d_in[27];
    p.bd3  = (const float*)d_in[28];
    p.gd3  = (const float*)d_in[29];
    p.ed3  = (const float*)d_in[30];
    p.gf   = (const float*)d_in[31];
    p.ef   = (const float*)d_in[32];
    p.Wf   = (const float*)d_in[33];
    p.bf   = (const float*)d_in[34];
    p.ga   = (const float*)d_in[35];
    p.ea   = (const float*)d_in[36];
    p.Wa   = (const float*)d_in[37];
    p.ba   = (const float*)d_in[38];
    p.Wo   = (const float*)d_in[39];
    p.bo   = (const float*)d_in[40];
    p.out  = (float*)d_out;

    float* W = (float*)d_ws;
    p.gene_n = W;                         // 3000*256
    p.drug_n = p.gene_n + 3000 * NB;      // 2048*256
    p.h1i    = p.drug_n + 2048 * NB;      // 1500*6*256 (interleaved by 6)
    p.h2i    = p.h1i    + 9000 * NB;      // 400*6*256  (interleaved by 6)
    p.fbn    = p.h2i    + 2400 * NB;      // 56*256
    p.d1n    = p.fbn    + 56 * NB;        // 128*256
    p.d2n    = p.d1n    + 128 * NB;       // 64*256
    p.o1n    = p.d2n    + 64 * NB;        // 64*256
    p.part2  = p.o1n    + 64 * NB;        // 16*24*256
    p.part1  = p.part2  + 16 * 24 * NB;   // 128*8*256
    p.bar    = (unsigned int*)(p.part1 + 128 * 8 * NB);

    // zero the barrier counter (graph-capturable async memset)
    hipMemsetAsync((void*)p.bar, 0, 64, stream);

    k_mega<<<dim3(NBLK), dim3(256), 0, stream>>>(p);
}